// Round 5
// baseline (468.637 us; speedup 1.0000x reference)
//
#include <hip/hip_runtime.h>

typedef __bf16 bf16;
typedef __bf16 bf16x8 __attribute__((ext_vector_type(8)));
typedef float floatx4 __attribute__((ext_vector_type(4)));

#define MFMA_BF16(a, b, c) __builtin_amdgcn_mfma_f32_16x16x32_bf16((a), (b), (c), 0, 0, 0)

// async global->LDS, 16B per lane; LDS dest = wave-uniform base + lane*16
#define GLOAD_LDS16(gp, lp)                                      \
  __builtin_amdgcn_global_load_lds(                              \
      (const __attribute__((address_space(1))) void*)(gp),       \
      (__attribute__((address_space(3))) void*)(lp), 16, 0, 0)

// Problem constants: B=4, T=2048, C=1024, H=16, hd=64; M = B*T = 8192
#define SEQ_T 2048
#define DIM_C 1024
#define HDIM 64
#define MROWS 8192
#define N_QKV 3072

// ---------------- x fp32 -> bf16 ----------------
__global__ __launch_bounds__(256) void f32_to_bf16(
    const float* __restrict__ in, bf16* __restrict__ out) {
  const size_t i = ((size_t)blockIdx.x * 256 + threadIdx.x) * 8;
  const float4 f0 = *(const float4*)&in[i];
  const float4 f1 = *(const float4*)&in[i + 4];
  bf16x8 v;
  v[0] = (bf16)f0.x; v[1] = (bf16)f0.y; v[2] = (bf16)f0.z; v[3] = (bf16)f0.w;
  v[4] = (bf16)f1.x; v[5] = (bf16)f1.y; v[6] = (bf16)f1.z; v[7] = (bf16)f1.w;
  *(bf16x8*)&out[i] = v;
}

// ---------------- transpose fp32 -> bf16: out[N][K] = (bf16)in[K][N] ----------------
__global__ __launch_bounds__(256) void transpose_f32_bf16(
    const float* __restrict__ in, bf16* __restrict__ out, int R, int C) {
  __shared__ bf16 tile[32][33];
  const int bx = blockIdx.x * 32, by = blockIdx.y * 32;
  const int tx = threadIdx.x & 31, ty = threadIdx.x >> 5;
  for (int i = 0; i < 32; i += 8)
    tile[ty + i][tx] = (bf16)in[(size_t)(by + ty + i) * C + bx + tx];
  __syncthreads();
  for (int i = 0; i < 32; i += 8)
    out[(size_t)(bx + ty + i) * R + by + tx] = tile[tx][ty + i];
}

// ---------------- GEMM (m97 structure): Cout = A[M][K] @ Bt[N][K]^T + bias ----------------
template <typename OT>
__global__ __launch_bounds__(256) void gemm_lds(
    const bf16* __restrict__ A,     // M x K row-major (bf16)
    const bf16* __restrict__ Bt,    // N x K row-major (bf16)
    const float* __restrict__ bias, // N (fp32)
    OT* __restrict__ Cout,          // M x N row-major
    int M, int N, int K) {
  __shared__ __align__(16) bf16 Asl[128 * 32];  // seg s: row=s>>2, phys block=s&3
  __shared__ __align__(16) bf16 Bsl[128 * 32];  // content block = (s&3) ^ (row&3)
  const int bm = blockIdx.y * 128, bn = blockIdx.x * 128;
  const int tid = threadIdx.x;
  const int wave = tid >> 6, lane = tid & 63;
  const int wm = (wave >> 1) * 64, wn = (wave & 1) * 64;
  const int quad = lane >> 4, l16 = lane & 15;

  const floatx4 zero = {0.f, 0.f, 0.f, 0.f};
  floatx4 acc[4][4];
  for (int i = 0; i < 4; i++)
    for (int j = 0; j < 4; j++) acc[i][j] = zero;

  const int s0 = tid, s1 = 256 + tid;
  const int r0 = s0 >> 2, lb0 = (s0 & 3) ^ (r0 & 3);
  const int r1 = s1 >> 2, lb1 = (s1 & 3) ^ (r1 & 3);
  const bf16* ga0 = &A[(size_t)(bm + r0) * K + lb0 * 8];
  const bf16* ga1 = &A[(size_t)(bm + r1) * K + lb1 * 8];
  const bf16* gb0 = &Bt[(size_t)(bn + r0) * K + lb0 * 8];
  const bf16* gb1 = &Bt[(size_t)(bn + r1) * K + lb1 * 8];
  bf16* lds0 = &Asl[(wave * 64) * 8];
  bf16* lds1 = &Asl[(256 + wave * 64) * 8];
  bf16* ldsB0 = &Bsl[(wave * 64) * 8];
  bf16* ldsB1 = &Bsl[(256 + wave * 64) * 8];

  for (int k0 = 0; k0 < K; k0 += 32) {
    GLOAD_LDS16(ga0 + k0, lds0);
    GLOAD_LDS16(ga1 + k0, lds1);
    GLOAD_LDS16(gb0 + k0, ldsB0);
    GLOAD_LDS16(gb1 + k0, ldsB1);
    __syncthreads();
    bf16x8 af[4], bfr[4];
    for (int it = 0; it < 4; it++) {
      const int row = wm + it * 16 + l16;
      af[it] = *(const bf16x8*)&Asl[(row * 4 + (quad ^ (row & 3))) * 8];
    }
    for (int jt = 0; jt < 4; jt++) {
      const int row = wn + jt * 16 + l16;
      bfr[jt] = *(const bf16x8*)&Bsl[(row * 4 + (quad ^ (row & 3))) * 8];
    }
    for (int it = 0; it < 4; it++)
      for (int jt = 0; jt < 4; jt++)
        acc[it][jt] = MFMA_BF16(af[it], bfr[jt], acc[it][jt]);
    __syncthreads();
  }
  for (int jt = 0; jt < 4; jt++) {
    const int col = bn + wn + jt * 16 + l16;
    const float bv = bias[col];
    for (int it = 0; it < 4; it++)
      for (int r = 0; r < 4; r++) {
        const int row = bm + wm + it * 16 + quad * 4 + r;
        Cout[(size_t)row * N + col] = (OT)(acc[it][jt][r] + bv);
      }
  }
}

// ---------------- attention ----------------
// Block p: q-tiles qtA=p, qtB=31-p (paired triangle). Q frags + K frags in
// registers (K direct-from-global, single-buffer refilled after last use);
// only V (transposed+swizzled+k2-scaled) and P̂ round-trip through LDS.
// LDS 28.2 KB; VGPR capped for 4 waves/SIMD.
__global__ __launch_bounds__(256, 4) void attn_kernel(
    const bf16* __restrict__ qkv,  // 8192 x 3072 : [q | k | v]
    bf16* __restrict__ y) {        // 8192 x 1024
  const int p = blockIdx.x;            // 0..15
  const int bh = blockIdx.y;           // 0..63
  const int bb = bh >> 4, h = bh & 15;
  const int qtA = p, qtB = 31 - p;
  const int tid = threadIdx.x;
  const int wave = tid >> 6, lane = tid & 63;
  const int quad = lane >> 4, l16 = lane & 15;

  __shared__ __align__(16) bf16 Ps[128][72];   // rows 0..63 tile A, 64..127 tile B
  __shared__ __align__(16) bf16 Vt[64][72];    // [d][key ^ (d & 0x38)], k2-scaled
  __shared__ float q2c[128];                   // c2 * |q|^2 per q-row

  const size_t rowbase = (size_t)bb * SEQ_T;
  const float c2 = -0.09016844f;    // -1/16 * log2(e)
  const float m2c2 = 0.18033688f;   // -2*c2

  // ---- Q fragments in registers + q2c ----
  bf16x8 aq[2][2];
  for (int T = 0; T < 2; T++) {
    const int qt = T ? qtB : qtA;
    const size_t grow = rowbase + qt * 64 + wave * 16 + l16;
    float s = 0.f;
    for (int ks = 0; ks < 2; ks++) {
      aq[T][ks] = *(const bf16x8*)&qkv[grow * N_QKV + h * HDIM + ks * 32 + quad * 8];
      for (int j = 0; j < 8; j++) { const float f = (float)aq[T][ks][j]; s += f * f; }
    }
    s += __shfl_xor(s, 16); s += __shfl_xor(s, 32);
    if (quad == 0) q2c[T * 64 + wave * 16 + l16] = s * c2;
  }

  // ---- K fragment pointers (per-lane) + preload kt=0 ----
  // bk[jt][ks] = K[key = jt*16+l16][d = ks*32+quad*8 ..+7] of tile kt
  const bf16* kfb = &qkv[(rowbase + l16) * N_QKV + 1024 + h * HDIM + quad * 8];
  bf16x8 bk[4][2];
  for (int jt = 0; jt < 4; jt++)
    for (int ks = 0; ks < 2; ks++)
      bk[jt][ks] = *(const bf16x8*)&kfb[(size_t)(jt * 16) * N_QKV + ks * 32];

  const floatx4 zero = {0.f, 0.f, 0.f, 0.f};
  floatx4 accy[2][4];
  for (int T = 0; T < 2; T++)
    for (int jt = 0; jt < 4; jt++) accy[T][jt] = zero;

  for (int kt = 0; kt <= qtB; kt++) {
    const bool actA = (kt <= qtA);
    // ---- stage V transposed+swizzled, scaled by 2^(c2*k2) (K read only for k2) ----
    {
      const int r0 = tid >> 3, c8 = (tid & 7) << 3;
      for (int i = 0; i < 2; i++) {
        const int r = r0 + i * 32;
        const size_t gr = rowbase + (size_t)(kt * 64 + r);
        const bf16x8 kv = *(const bf16x8*)&qkv[gr * N_QKV + 1024 + h * HDIM + c8];
        float s = 0.f;
        for (int j = 0; j < 8; j++) { const float f = (float)kv[j]; s += f * f; }
        s += __shfl_xor(s, 1); s += __shfl_xor(s, 2); s += __shfl_xor(s, 4);
        const float vscale = exp2f(s * c2);
        const bf16x8 vv = *(const bf16x8*)&qkv[gr * N_QKV + 2048 + h * HDIM + c8];
        for (int j = 0; j < 8; j++)
          Vt[c8 + j][r ^ c8] = (bf16)((float)vv[j] * vscale);
      }
    }
    __syncthreads();  // Vt visible (also publishes q2c at kt=0)

    // ---- S = Q.K^T (bk already in registers) ----
    floatx4 accs[2][4];
    for (int T = 0; T < 2; T++)
      for (int jt = 0; jt < 4; jt++) accs[T][jt] = zero;
    for (int T = 0; T < 2; T++) {
      if (T == 0 && !actA) continue;
      for (int ks = 0; ks < 2; ks++)
        for (int jt = 0; jt < 4; jt++)
          accs[T][jt] = MFMA_BF16(aq[T][ks], bk[jt][ks], accs[T][jt]);
    }

    // ---- refill bk for kt+1 (last use was above; latency hidden by P̂) ----
    if (kt < qtB) {
      const bf16* kfn = kfb + (size_t)(kt + 1) * 64 * N_QKV;
      for (int jt = 0; jt < 4; jt++)
        for (int ks = 0; ks < 2; ks++)
          bk[jt][ks] = *(const bf16x8*)&kfn[(size_t)(jt * 16) * N_QKV + ks * 32];
    }

    // ---- P̂ = 2^(m2c2*qk), mask on diagonal tile; wave-private Ps rows ----
    for (int T = 0; T < 2; T++) {
      if (T == 0 && !actA) continue;
      const bool diag = (kt == (T == 0 ? qtA : qtB));
      for (int jt = 0; jt < 4; jt++) {
        const int nl = jt * 16 + l16;
        for (int r = 0; r < 4; r++) {
          const int ml = wave * 16 + quad * 4 + r;
          float pe = exp2f(m2c2 * accs[T][jt][r]);
          if (diag && nl > ml) pe = 0.f;
          Ps[T * 64 + ml][nl] = (bf16)pe;
        }
      }
    }

    // ---- y += P̂ . Ṽ (bv hoisted: loaded once, used by both tiles) ----
    bf16x8 bv[4][2];
    for (int jt = 0; jt < 4; jt++)
      for (int ks = 0; ks < 2; ks++) {
        const int d = jt * 16 + l16;
        bv[jt][ks] = *(const bf16x8*)&Vt[d][(ks * 32 + quad * 8) ^ (d & 0x38)];
      }
    for (int T = 0; T < 2; T++) {
      if (T == 0 && !actA) continue;
      for (int ks = 0; ks < 2; ks++) {
        const bf16x8 ap =
            *(const bf16x8*)&Ps[T * 64 + wave * 16 + l16][ks * 32 + quad * 8];
        for (int jt = 0; jt < 4; jt++)
          accy[T][jt] = MFMA_BF16(ap, bv[jt][ks], accy[T][jt]);
      }
    }
    __syncthreads();  // Vt reads done before next staging
  }

  // ---- epilogue: scale by 2^(c2*q2), store ----
  for (int T = 0; T < 2; T++) {
    const int qt = (T == 0) ? qtA : qtB;
    float ysc[4];
    for (int r = 0; r < 4; r++)
      ysc[r] = exp2f(q2c[T * 64 + wave * 16 + quad * 4 + r]);
    for (int jt = 0; jt < 4; jt++) {
      const int col = h * HDIM + jt * 16 + l16;
      for (int r = 0; r < 4; r++) {
        const int ml = wave * 16 + quad * 4 + r;
        y[(rowbase + qt * 64 + ml) * DIM_C + col] = (bf16)(accy[T][jt][r] * ysc[r]);
      }
    }
  }
}

extern "C" void kernel_launch(void* const* d_in, const int* in_sizes, int n_in,
                              void* d_out, int out_size, void* d_ws, size_t ws_size,
                              hipStream_t stream) {
  const float* x      = (const float*)d_in[0];  // 8192 x 1024 fp32
  const float* W_attn = (const float*)d_in[1];  // 1024 x 3072 fp32
  const float* b_attn = (const float*)d_in[2];  // 3072 fp32
  const float* W_proj = (const float*)d_in[3];  // 1024 x 1024 fp32
  const float* b_proj = (const float*)d_in[4];  // 1024 fp32
  float* out = (float*)d_out;                   // 8192 x 1024 fp32

  char* ws = (char*)d_ws;
  bf16* qkv = (bf16*)(ws);             // 50,331,648 B
  bf16* yb  = (bf16*)(ws + 50331648);  // 16,777,216 B — also holds xb before attn
  bf16* WaT = (bf16*)(ws + 67108864);  //  6,291,456 B
  bf16* WpT = (bf16*)(ws + 73400320);  //  2,097,152 B  (total 75,497,472)
  bf16* xb  = yb;                      // x-bf16 is dead before attn writes yb

  f32_to_bf16<<<dim3(4096), 256, 0, stream>>>(x, xb);
  transpose_f32_bf16<<<dim3(96, 32), 256, 0, stream>>>(W_attn, WaT, 1024, 3072);
  transpose_f32_bf16<<<dim3(32, 32), 256, 0, stream>>>(W_proj, WpT, 1024, 1024);
  gemm_lds<bf16><<<dim3(24, 64), 256, 0, stream>>>(
      xb, WaT, b_attn, qkv, MROWS, N_QKV, DIM_C);
  attn_kernel<<<dim3(16, 64), 256, 0, stream>>>(qkv, yb);
  gemm_lds<float><<<dim3(8, 64), 256, 0, stream>>>(
      yb, WpT, b_proj, out, MROWS, DIM_C, DIM_C);
}

// Round 6
// 303.008 us; speedup vs baseline: 1.5466x; 1.5466x over previous
//
#include <hip/hip_runtime.h>

typedef __bf16 bf16;
typedef __bf16 bf16x8 __attribute__((ext_vector_type(8)));
typedef float floatx4 __attribute__((ext_vector_type(4)));

#define MFMA_BF16(a, b, c) __builtin_amdgcn_mfma_f32_16x16x32_bf16((a), (b), (c), 0, 0, 0)

// async global->LDS, 16B per lane; LDS dest = wave-uniform base + lane*16
#define GLOAD_LDS16(gp, lp)                                      \
  __builtin_amdgcn_global_load_lds(                              \
      (const __attribute__((address_space(1))) void*)(gp),       \
      (__attribute__((address_space(3))) void*)(lp), 16, 0, 0)

// Problem constants: B=4, T=2048, C=1024, H=16, hd=64; M = B*T = 8192
#define SEQ_T 2048
#define DIM_C 1024
#define HDIM 64
#define MROWS 8192
#define N_QKV 3072

// ---------------- x fp32 -> bf16 ----------------
__global__ __launch_bounds__(256) void f32_to_bf16(
    const float* __restrict__ in, bf16* __restrict__ out) {
  const size_t i = ((size_t)blockIdx.x * 256 + threadIdx.x) * 8;
  const float4 f0 = *(const float4*)&in[i];
  const float4 f1 = *(const float4*)&in[i + 4];
  bf16x8 v;
  v[0] = (bf16)f0.x; v[1] = (bf16)f0.y; v[2] = (bf16)f0.z; v[3] = (bf16)f0.w;
  v[4] = (bf16)f1.x; v[5] = (bf16)f1.y; v[6] = (bf16)f1.z; v[7] = (bf16)f1.w;
  *(bf16x8*)&out[i] = v;
}

// ---------------- transpose fp32 -> bf16: out[N][K] = (bf16)in[K][N] ----------------
__global__ __launch_bounds__(256) void transpose_f32_bf16(
    const float* __restrict__ in, bf16* __restrict__ out, int R, int C) {
  __shared__ bf16 tile[32][33];
  const int bx = blockIdx.x * 32, by = blockIdx.y * 32;
  const int tx = threadIdx.x & 31, ty = threadIdx.x >> 5;
  for (int i = 0; i < 32; i += 8)
    tile[ty + i][tx] = (bf16)in[(size_t)(by + ty + i) * C + bx + tx];
  __syncthreads();
  for (int i = 0; i < 32; i += 8)
    out[(size_t)(bx + ty + i) * R + by + tx] = tile[tx][ty + i];
}

// ---------------- GEMM (m97 structure, BK=64): Cout = A @ Bt^T + bias ----------------
// 128x128 tile, BK=64 (16 k-iters for K=1024 -> half the barriers of BK=32),
// global_load_lds width-16 staging, XOR-8 block swizzle. LDS 32 KB.
template <typename OT>
__global__ __launch_bounds__(256) void gemm_lds(
    const bf16* __restrict__ A,     // M x K row-major (bf16)
    const bf16* __restrict__ Bt,    // N x K row-major (bf16)
    const float* __restrict__ bias, // N (fp32)
    OT* __restrict__ Cout,          // M x N row-major
    int M, int N, int K) {
  __shared__ __align__(16) bf16 Asl[128 * 64];  // seg s: row=s>>3, phys blk=s&7
  __shared__ __align__(16) bf16 Bsl[128 * 64];  // content blk = (s&7) ^ (row&7)
  const int bm = blockIdx.y * 128, bn = blockIdx.x * 128;
  const int tid = threadIdx.x;
  const int wave = tid >> 6, lane = tid & 63;
  const int wm = (wave >> 1) * 64, wn = (wave & 1) * 64;
  const int quad = lane >> 4, l16 = lane & 15;

  const floatx4 zero = {0.f, 0.f, 0.f, 0.f};
  floatx4 acc[4][4];
  for (int i = 0; i < 4; i++)
    for (int j = 0; j < 4; j++) acc[i][j] = zero;

  // per-lane global pointers; seg s = i*256 + tid
  const bf16 *gA[4], *gB[4];
  bf16 *lA[4], *lB[4];
  for (int i = 0; i < 4; i++) {
    const int s = i * 256 + tid;
    const int row = s >> 3;
    const int c = (s & 7) ^ (row & 7);     // content block stored at phys s&7
    gA[i] = &A[(size_t)(bm + row) * K + c * 8];
    gB[i] = &Bt[(size_t)(bn + row) * K + c * 8];
    lA[i] = &Asl[(i * 256 + wave * 64) * 8];  // wave-uniform bases
    lB[i] = &Bsl[(i * 256 + wave * 64) * 8];
  }

  for (int k0 = 0; k0 < K; k0 += 64) {
    for (int i = 0; i < 4; i++) GLOAD_LDS16(gA[i] + k0, lA[i]);
    for (int i = 0; i < 4; i++) GLOAD_LDS16(gB[i] + k0, lB[i]);
    __syncthreads();
    for (int kk = 0; kk < 2; kk++) {
      bf16x8 af[4], bfr[4];
      for (int it = 0; it < 4; it++) {
        const int row = wm + it * 16 + l16;
        const int phys = (kk * 4 + quad) ^ (row & 7);
        af[it] = *(const bf16x8*)&Asl[row * 64 + phys * 8];
      }
      for (int jt = 0; jt < 4; jt++) {
        const int row = wn + jt * 16 + l16;
        const int phys = (kk * 4 + quad) ^ (row & 7);
        bfr[jt] = *(const bf16x8*)&Bsl[row * 64 + phys * 8];
      }
      for (int it = 0; it < 4; it++)
        for (int jt = 0; jt < 4; jt++)
          acc[it][jt] = MFMA_BF16(af[it], bfr[jt], acc[it][jt]);
    }
    __syncthreads();
  }
  // C/D layout: row = quad*4+reg, col = l16
  for (int jt = 0; jt < 4; jt++) {
    const int col = bn + wn + jt * 16 + l16;
    const float bv = bias[col];
    for (int it = 0; it < 4; it++)
      for (int r = 0; r < 4; r++) {
        const int row = bm + wm + it * 16 + quad * 4 + r;
        Cout[(size_t)row * N + col] = (OT)(acc[it][jt][r] + bv);
      }
  }
}

// ---------------- attention (R4 version — proven 123 us) ----------------
// Block p: q-tiles qtA=p, qtB=31-p (paired triangle, uniform work). Q frags in
// registers (wave-private rows); exp factored: P̂=2^(m2c2·qk), V rows pre-scaled
// by 2^(c2·k2), epilogue scaled by 2^(c2·q2). LDS 37.5 KB -> 4 blocks/CU.
__global__ __launch_bounds__(256, 4) void attn_kernel(
    const bf16* __restrict__ qkv,  // 8192 x 3072 : [q | k | v]
    bf16* __restrict__ y) {        // 8192 x 1024
  const int p = blockIdx.x;            // 0..15
  const int bh = blockIdx.y;           // 0..63
  const int bb = bh >> 4, h = bh & 15;
  const int qtA = p, qtB = 31 - p;
  const int tid = threadIdx.x;
  const int wave = tid >> 6, lane = tid & 63;
  const int quad = lane >> 4, l16 = lane & 15;

  __shared__ __align__(16) bf16 Ps[128][72];   // rows 0..63 tile A, 64..127 tile B
  __shared__ __align__(16) bf16 Ks[64][72];
  __shared__ __align__(16) bf16 Vt[64][72];    // [d][key ^ (d & 0x38)], k2-scaled
  __shared__ float q2c[128];                   // c2 * |q|^2 per q-row

  const size_t rowbase = (size_t)bb * SEQ_T;
  const float c2 = -0.09016844f;    // -1/16 * log2(e)
  const float m2c2 = 0.18033688f;   // -2*c2

  // ---- Q fragments in registers + q2c (shfl across quads) ----
  bf16x8 aq[2][2];
  for (int T = 0; T < 2; T++) {
    const int qt = T ? qtB : qtA;
    const size_t grow = rowbase + qt * 64 + wave * 16 + l16;
    float s = 0.f;
    for (int ks = 0; ks < 2; ks++) {
      aq[T][ks] = *(const bf16x8*)&qkv[grow * N_QKV + h * HDIM + ks * 32 + quad * 8];
      for (int j = 0; j < 8; j++) { const float f = (float)aq[T][ks][j]; s += f * f; }
    }
    s += __shfl_xor(s, 16); s += __shfl_xor(s, 32);
    if (quad == 0) q2c[T * 64 + wave * 16 + l16] = s * c2;
  }

  const floatx4 zero = {0.f, 0.f, 0.f, 0.f};
  floatx4 accy[2][4];
  for (int T = 0; T < 2; T++)
    for (int jt = 0; jt < 4; jt++) accy[T][jt] = zero;

  for (int kt = 0; kt <= qtB; kt++) {
    const bool actA = (kt <= qtA);
    // ---- stage K row-major; V transposed+swizzled, scaled by 2^(c2*k2) ----
    {
      const int r0 = tid >> 3, c8 = (tid & 7) << 3;
      for (int i = 0; i < 2; i++) {
        const int r = r0 + i * 32;
        const size_t gr = rowbase + (size_t)(kt * 64 + r);
        const bf16x8 kv = *(const bf16x8*)&qkv[gr * N_QKV + 1024 + h * HDIM + c8];
        *(bf16x8*)&Ks[r][c8] = kv;
        float s = 0.f;
        for (int j = 0; j < 8; j++) { const float f = (float)kv[j]; s += f * f; }
        s += __shfl_xor(s, 1); s += __shfl_xor(s, 2); s += __shfl_xor(s, 4);
        const float vscale = exp2f(s * c2);
        const bf16x8 vv = *(const bf16x8*)&qkv[gr * N_QKV + 2048 + h * HDIM + c8];
        for (int j = 0; j < 8; j++)
          Vt[c8 + j][r ^ c8] = (bf16)((float)vv[j] * vscale);
      }
    }
    __syncthreads();  // staging visible (also publishes q2c at kt=0)

    // ---- S = Q.K^T ----
    bf16x8 bk[4][2];
    for (int jt = 0; jt < 4; jt++)
      for (int ks = 0; ks < 2; ks++)
        bk[jt][ks] = *(const bf16x8*)&Ks[jt * 16 + l16][ks * 32 + quad * 8];
    floatx4 accs[2][4];
    for (int T = 0; T < 2; T++)
      for (int jt = 0; jt < 4; jt++) accs[T][jt] = zero;
    for (int T = 0; T < 2; T++) {
      if (T == 0 && !actA) continue;
      for (int ks = 0; ks < 2; ks++)
        for (int jt = 0; jt < 4; jt++)
          accs[T][jt] = MFMA_BF16(aq[T][ks], bk[jt][ks], accs[T][jt]);
    }

    // ---- P̂ = 2^(m2c2*qk), mask on diagonal tile; wave-private Ps rows ----
    for (int T = 0; T < 2; T++) {
      if (T == 0 && !actA) continue;
      const bool diag = (kt == (T == 0 ? qtA : qtB));
      for (int jt = 0; jt < 4; jt++) {
        const int nl = jt * 16 + l16;
        for (int r = 0; r < 4; r++) {
          const int ml = wave * 16 + quad * 4 + r;
          float pe = exp2f(m2c2 * accs[T][jt][r]);
          if (diag && nl > ml) pe = 0.f;
          Ps[T * 64 + ml][nl] = (bf16)pe;
        }
      }
    }

    // ---- y += P̂ . Ṽ (bv loaded once, used by both tiles) ----
    bf16x8 bv[4][2];
    for (int jt = 0; jt < 4; jt++)
      for (int ks = 0; ks < 2; ks++) {
        const int d = jt * 16 + l16;
        bv[jt][ks] = *(const bf16x8*)&Vt[d][(ks * 32 + quad * 8) ^ (d & 0x38)];
      }
    for (int T = 0; T < 2; T++) {
      if (T == 0 && !actA) continue;
      for (int ks = 0; ks < 2; ks++) {
        const bf16x8 ap =
            *(const bf16x8*)&Ps[T * 64 + wave * 16 + l16][ks * 32 + quad * 8];
        for (int jt = 0; jt < 4; jt++)
          accy[T][jt] = MFMA_BF16(ap, bv[jt][ks], accy[T][jt]);
      }
    }
    __syncthreads();  // Ks/Vt reads done before next staging
  }

  // ---- epilogue: scale by 2^(c2*q2), store ----
  for (int T = 0; T < 2; T++) {
    const int qt = (T == 0) ? qtA : qtB;
    float ysc[4];
    for (int r = 0; r < 4; r++)
      ysc[r] = exp2f(q2c[T * 64 + wave * 16 + quad * 4 + r]);
    for (int jt = 0; jt < 4; jt++) {
      const int col = h * HDIM + jt * 16 + l16;
      for (int r = 0; r < 4; r++) {
        const int ml = wave * 16 + quad * 4 + r;
        y[(rowbase + qt * 64 + ml) * DIM_C + col] = (bf16)(accy[T][jt][r] * ysc[r]);
      }
    }
  }
}

extern "C" void kernel_launch(void* const* d_in, const int* in_sizes, int n_in,
                              void* d_out, int out_size, void* d_ws, size_t ws_size,
                              hipStream_t stream) {
  const float* x      = (const float*)d_in[0];  // 8192 x 1024 fp32
  const float* W_attn = (const float*)d_in[1];  // 1024 x 3072 fp32
  const float* b_attn = (const float*)d_in[2];  // 3072 fp32
  const float* W_proj = (const float*)d_in[3];  // 1024 x 1024 fp32
  const float* b_proj = (const float*)d_in[4];  // 1024 fp32
  float* out = (float*)d_out;                   // 8192 x 1024 fp32

  char* ws = (char*)d_ws;
  bf16* qkv = (bf16*)(ws);             // 50,331,648 B
  bf16* yb  = (bf16*)(ws + 50331648);  // 16,777,216 B — also holds xb before attn
  bf16* WaT = (bf16*)(ws + 67108864);  //  6,291,456 B
  bf16* WpT = (bf16*)(ws + 73400320);  //  2,097,152 B  (total 75,497,472)
  bf16* xb  = yb;                      // x-bf16 is dead before attn writes yb

  f32_to_bf16<<<dim3(4096), 256, 0, stream>>>(x, xb);
  transpose_f32_bf16<<<dim3(96, 32), 256, 0, stream>>>(W_attn, WaT, 1024, 3072);
  transpose_f32_bf16<<<dim3(32, 32), 256, 0, stream>>>(W_proj, WpT, 1024, 1024);
  gemm_lds<bf16><<<dim3(24, 64), 256, 0, stream>>>(
      xb, WaT, b_attn, qkv, MROWS, N_QKV, DIM_C);
  attn_kernel<<<dim3(16, 64), 256, 0, stream>>>(qkv, yb);
  gemm_lds<float><<<dim3(8, 64), 256, 0, stream>>>(
      yb, WpT, b_proj, out, MROWS, DIM_C, DIM_C);
}